// Round 5
// baseline (300.611 us; speedup 1.0000x reference)
//
#include <hip/hip_runtime.h>
#include <hip/hip_bf16.h>
#include <hip/hip_cooperative_groups.h>
#include <math.h>

namespace cg = cooperative_groups;

constexpr int NP  = 6144;   // rows
constexpr int DM  = 256;    // d_model
constexpr int DFF = 1024;   // ff dim
constexpr float LNEPS = 1e-5f;

typedef __attribute__((ext_vector_type(8))) short short8;
typedef __attribute__((ext_vector_type(4))) float f32x4;

__device__ __forceinline__ short f2bf(float f) {
    unsigned u = __builtin_bit_cast(unsigned, f);
    unsigned r = u + 0x7FFFu + ((u >> 16) & 1u);   // RNE
    return (short)(r >> 16);
}
__device__ __forceinline__ float bf2f(short s) {
    unsigned u = ((unsigned)(unsigned short)s) << 16;
    return __builtin_bit_cast(float, u);
}

// global->LDS direct 16B copy. LDS dest = wave-uniform base + lane*16;
// per-lane global src carries the swizzle (guide rule #21).
#define GLOAD16(gp, lp)                                                        \
    __builtin_amdgcn_global_load_lds(                                          \
        (const __attribute__((address_space(1))) unsigned int*)(gp),           \
        (__attribute__((address_space(3))) unsigned int*)(lp), 16, 0, 0)

// LDS tile: linear [rows][64] shorts (128B row = 8 x 16B chunks); chunk c of
// row r stored at slot c ^ (r&7). Returns short index for global chunk c.
__device__ __forceinline__ int lds_idx(int row, int chunk) {
    return row * 64 + ((chunk ^ (row & 7)) * 8);
}

union SMem {
    struct { short As[192 * 64]; short Bs[128 * 64]; } g;   // 40960 B
    struct { short As[32 * 64];  short Bs[256 * 64];
             float r1[8][32]; float r2[8][32]; } l;          // 38912 B
    struct { float w[32][33]; } p;                           // 4224 B
};

__global__ __launch_bounds__(512, 1) void fused_layer(
    const float* __restrict__ x, const int* __restrict__ dom,
    const float* __restrict__ qkv_w, const float* __restrict__ qkv_b,
    const float* __restrict__ out_w, const float* __restrict__ out_b,
    const float* __restrict__ ff_w1, const float* __restrict__ ff_b1,
    const float* __restrict__ ff_w2, const float* __restrict__ ff_b2,
    const float* __restrict__ ln1_g, const float* __restrict__ ln1_b,
    const float* __restrict__ ln2_g, const float* __restrict__ ln2_b,
    float* __restrict__ out,
    short* xB, short* qkvB, short* attn_o, short* x1, short* hB,
    short* qkvT, short* outT, short* ff1T, short* ff2T,
    int* seg_s, int* seg_e) {
    cg::grid_group grid = cg::this_grid();
    __shared__ SMem sm;

    const int tid  = threadIdx.x;
    const int lane = tid & 63;
    const int w    = tid >> 6;              // wave 0..7
    const int lr   = lane >> 3;             // staging row-in-8
    const int sc   = (lane & 7) ^ lr;       // swizzled source chunk
    const int fr   = lane & 15;             // fragment row / C col
    const int g4   = lane >> 4;             // lane quarter

    // ================= P0: prep =================
    // weights fp32[K][N] -> bf16[N][K]; 768 32x32 tiles, 3 per block
    for (int tt = 0; tt < 3; ++tt) {
        int b = blockIdx.x * 3 + tt;
        const float* src; short* dst; int K, Nn;
        if (b < 192)      { src = qkv_w; dst = qkvT; K = 256;  Nn = 768; }
        else if (b < 256) { b -= 192; src = out_w; dst = outT; K = 256;  Nn = 256; }
        else if (b < 512) { b -= 256; src = ff_w1; dst = ff1T; K = 256;  Nn = 1024; }
        else              { b -= 512; src = ff_w2; dst = ff2T; K = 1024; Nn = 256; }
        int tpr = Nn / 32, k0 = (b / tpr) * 32, n0 = (b % tpr) * 32;
        __syncthreads();
        {
            int k = tid >> 4, n = (tid & 15) * 2;
            *(float2*)&sm.p.w[k][n] =
                *(const float2*)&src[(size_t)(k0 + k) * Nn + n0 + n];
        }
        __syncthreads();
        {
            int n = tid >> 4, ks = (tid & 15) * 2;
            short* d = &dst[(size_t)(n0 + n) * K + k0 + ks];
            d[0] = f2bf(sm.p.w[ks][n]);
            d[1] = f2bf(sm.p.w[ks + 1][n]);
        }
    }
    // x -> bf16 (grid-stride, 8/thread)
    for (size_t i = ((size_t)blockIdx.x * 512 + tid) * 8; i < (size_t)NP * DM;
         i += (size_t)256 * 512 * 8) {
        float4 a0 = *(const float4*)&x[i];
        float4 a1 = *(const float4*)&x[i + 4];
        short8 v = { f2bf(a0.x), f2bf(a0.y), f2bf(a0.z), f2bf(a0.w),
                     f2bf(a1.x), f2bf(a1.y), f2bf(a1.z), f2bf(a1.w) };
        *(short8*)&xB[i] = v;
    }
    // segment bounds (sorted doc ids)
    {
        int i = blockIdx.x * 512 + tid;
        if (i < NP) {
            int d = dom[i];
            int s = i;
            while (s > 0 && dom[s - 1] == d) --s;
            int e = i + 1;
            while (e < NP && dom[e] == d) ++e;
            seg_s[i] = s;
            seg_e[i] = e;
        }
    }
    grid.sync();

    // ---- shared GEMM phase: C_bf16 = A_bf16 @ Bt^T + bias (opt GELU) ----
    // tile 192x128, 8 waves (4x2), wave tile 48x64 = 3x4 frags.
    auto gemm192 = [&](const short* A, const short* Bt, const float* bias,
                       short* C, int Nn, int K, bool gelu) {
        int tiles_n = Nn >> 7;
        int tile = blockIdx.x;
        if (tile >= 32 * tiles_n) return;
        int rowBase = (tile / tiles_n) * 192, colBase = (tile % tiles_n) * 128;
        int wm = (w >> 1) * 48, wn = (w & 1) * 64;

        f32x4 acc[3][4];
#pragma unroll
        for (int i = 0; i < 3; ++i)
#pragma unroll
            for (int j = 0; j < 4; ++j) acc[i][j] = f32x4{0.f, 0.f, 0.f, 0.f};

        for (int k0 = 0; k0 < K; k0 += 64) {
#pragma unroll
            for (int gi = 0; gi < 5; ++gi) {          // 40 groups: A 24, B 16
                int g = w * 5 + gi;
                if (g < 24)
                    GLOAD16(A + (size_t)(rowBase + g * 8 + lr) * K + k0 + sc * 8,
                            &sm.g.As[g * 512]);
                else
                    GLOAD16(Bt + (size_t)(colBase + (g - 24) * 8 + lr) * K + k0 + sc * 8,
                            &sm.g.Bs[(g - 24) * 512]);
            }
            __syncthreads();
#pragma unroll
            for (int kk = 0; kk < 2; ++kk) {
                int j = kk * 4 + g4;
                short8 af[3], bfv[4];
#pragma unroll
                for (int f = 0; f < 3; ++f)
                    af[f] = *(const short8*)&sm.g.As[lds_idx(wm + f * 16 + fr, j)];
#pragma unroll
                for (int f = 0; f < 4; ++f)
                    bfv[f] = *(const short8*)&sm.g.Bs[lds_idx(wn + f * 16 + fr, j)];
#pragma unroll
                for (int fm = 0; fm < 3; ++fm)
#pragma unroll
                    for (int fn = 0; fn < 4; ++fn)
                        acc[fm][fn] = __builtin_amdgcn_mfma_f32_16x16x32_bf16(
                            af[fm], bfv[fn], acc[fm][fn], 0, 0, 0);
            }
            __syncthreads();
        }
#pragma unroll
        for (int fm = 0; fm < 3; ++fm)
#pragma unroll
            for (int fn = 0; fn < 4; ++fn) {
                int c = colBase + wn + fn * 16 + fr;
                float bv = bias[c];
#pragma unroll
                for (int j = 0; j < 4; ++j) {
                    int r = rowBase + wm + fm * 16 + g4 * 4 + j;
                    float v = acc[fm][fn][j] + bv;
                    if (gelu) v = 0.5f * v * (1.0f + erff(v * 0.70710678118654752f));
                    C[(size_t)r * Nn + c] = f2bf(v);
                }
            }
    };

    // ---- fused GEMM + residual + LayerNorm (Nn=256 full rows) ----
    // tile 32x256, 8 waves; wave w owns cols [w*32, w*32+32) = 2x2 frags.
    auto gemmLN = [&](const short* A, const short* Bt, const float* bias,
                      const void* resv, bool resbf, const float* gw,
                      const float* bw, void* Cv, bool outbf, int K) {
        int tile = blockIdx.x;
        if (tile >= 192) return;
        int rowBase = tile * 32;

        f32x4 acc[2][2];
#pragma unroll
        for (int i = 0; i < 2; ++i)
#pragma unroll
            for (int j = 0; j < 2; ++j) acc[i][j] = f32x4{0.f, 0.f, 0.f, 0.f};

        for (int k0 = 0; k0 < K; k0 += 64) {
            for (int g = w; g < 36; g += 8) {         // A 4 groups, B 32 groups
                if (g < 4)
                    GLOAD16(A + (size_t)(rowBase + g * 8 + lr) * K + k0 + sc * 8,
                            &sm.l.As[g * 512]);
                else
                    GLOAD16(Bt + (size_t)((g - 4) * 8 + lr) * K + k0 + sc * 8,
                            &sm.l.Bs[(g - 4) * 512]);
            }
            __syncthreads();
#pragma unroll
            for (int kk = 0; kk < 2; ++kk) {
                int j = kk * 4 + g4;
                short8 af[2], bfv[2];
                af[0] = *(const short8*)&sm.l.As[lds_idx(fr, j)];
                af[1] = *(const short8*)&sm.l.As[lds_idx(16 + fr, j)];
#pragma unroll
                for (int fn = 0; fn < 2; ++fn)
                    bfv[fn] = *(const short8*)&sm.l.Bs[lds_idx(w * 32 + fn * 16 + fr, j)];
#pragma unroll
                for (int fm = 0; fm < 2; ++fm)
#pragma unroll
                    for (int fn = 0; fn < 2; ++fn)
                        acc[fm][fn] = __builtin_amdgcn_mfma_f32_16x16x32_bf16(
                            af[fm], bfv[fn], acc[fm][fn], 0, 0, 0);
            }
            __syncthreads();
        }

        float v[2][2][4], p1[2][4], p2[2][4];
#pragma unroll
        for (int fm = 0; fm < 2; ++fm)
#pragma unroll
            for (int j = 0; j < 4; ++j) { p1[fm][j] = 0.f; p2[fm][j] = 0.f; }
#pragma unroll
        for (int fm = 0; fm < 2; ++fm)
#pragma unroll
            for (int fn = 0; fn < 2; ++fn) {
                int c = w * 32 + fn * 16 + fr;
                float bv = bias[c];
#pragma unroll
                for (int j = 0; j < 4; ++j) {
                    int r = rowBase + fm * 16 + g4 * 4 + j;
                    float t = acc[fm][fn][j] + bv;
                    if (resbf) t += bf2f(((const short*)resv)[(size_t)r * 256 + c]);
                    else       t += ((const float*)resv)[(size_t)r * 256 + c];
                    v[fm][fn][j] = t;
                    p1[fm][j] += t;
                    p2[fm][j] += t * t;
                }
            }
#pragma unroll
        for (int m = 1; m < 16; m <<= 1)
#pragma unroll
            for (int fm = 0; fm < 2; ++fm)
#pragma unroll
                for (int j = 0; j < 4; ++j) {
                    p1[fm][j] += __shfl_xor(p1[fm][j], m);
                    p2[fm][j] += __shfl_xor(p2[fm][j], m);
                }
        if (fr == 0) {
#pragma unroll
            for (int fm = 0; fm < 2; ++fm)
#pragma unroll
                for (int j = 0; j < 4; ++j) {
                    sm.l.r1[w][fm * 16 + g4 * 4 + j] = p1[fm][j];
                    sm.l.r2[w][fm * 16 + g4 * 4 + j] = p2[fm][j];
                }
        }
        __syncthreads();
#pragma unroll
        for (int fm = 0; fm < 2; ++fm)
#pragma unroll
            for (int j = 0; j < 4; ++j) {
                int rl = fm * 16 + g4 * 4 + j;
                int r = rowBase + rl;
                float s1 = 0.f, s2 = 0.f;
#pragma unroll
                for (int ww = 0; ww < 8; ++ww) { s1 += sm.l.r1[ww][rl]; s2 += sm.l.r2[ww][rl]; }
                float mu = s1 * (1.0f / 256.0f);
                float var = s2 * (1.0f / 256.0f) - mu * mu;
                float rstd = rsqrtf(var + LNEPS);
#pragma unroll
                for (int fn = 0; fn < 2; ++fn) {
                    int c = w * 32 + fn * 16 + fr;
                    float o = (v[fm][fn][j] - mu) * rstd * gw[c] + bw[c];
                    if (outbf) ((short*)Cv)[(size_t)r * 256 + c] = f2bf(o);
                    else       ((float*)Cv)[(size_t)r * 256 + c] = o;
                }
            }
        __syncthreads();
    };

    // ================= P1: qkv GEMM =================
    gemm192(xB, qkvT, qkv_b, qkvB, 768, 256, false);
    grid.sync();

    // ================= P2: segment attention =================
    {
        int gw2 = blockIdx.x * 8 + w;           // global wave 0..2047
        for (int tsk = gw2 * 12; tsk < gw2 * 12 + 12; ++tsk) {
            int row = tsk >> 2, h = tsk & 3;
            float qd = bf2f(qkvB[(size_t)row * 768 + h * 64 + lane]);
            int s = seg_s[row], e = seg_e[row];
            float m = -INFINITY, l = 0.0f, acc = 0.0f;
            for (int j = s; j < e; ++j) {
                float kd = bf2f(qkvB[(size_t)j * 768 + 256 + h * 64 + lane]);
                float prod = qd * kd;
#pragma unroll
                for (int off = 32; off; off >>= 1) prod += __shfl_xor(prod, off);
                float score = prod * 0.125f;    // 1/sqrt(64)
                float mn = fmaxf(m, score);
                float scale = __expf(m - mn);
                float p = __expf(score - mn);
                l = l * scale + p;
                acc = acc * scale + p * bf2f(qkvB[(size_t)j * 768 + 512 + h * 64 + lane]);
                m = mn;
            }
            attn_o[(size_t)row * 256 + h * 64 + lane] = f2bf(acc / l);
        }
    }
    grid.sync();

    // ================= P3: x1 = LN1(x + attn_o @ out_w + out_b) =================
    gemmLN(attn_o, outT, out_b, x, false, ln1_g, ln1_b, x1, true, 256);
    grid.sync();

    // ================= P4: h = gelu(x1 @ ff_w1 + ff_b1) =================
    gemm192(x1, ff1T, ff_b1, hB, 1024, 256, true);
    grid.sync();

    // ================= P5: out = LN2(x1 + h @ ff_w2 + ff_b2) =================
    gemmLN(hB, ff2T, ff_b2, x1, true, ln2_g, ln2_b, out, false, 1024);
}

// ---------------------------------------------------------------------------
extern "C" void kernel_launch(void* const* d_in, const int* in_sizes, int n_in,
                              void* d_out, int out_size, void* d_ws, size_t ws_size,
                              hipStream_t stream) {
    const float* x      = (const float*)d_in[0];
    const int*   dom    = (const int*)d_in[1];
    const float* qkv_w  = (const float*)d_in[2];
    const float* qkv_b  = (const float*)d_in[3];
    const float* out_w  = (const float*)d_in[4];
    const float* out_b  = (const float*)d_in[5];
    const float* ff_w1  = (const float*)d_in[6];
    const float* ff_b1  = (const float*)d_in[7];
    const float* ff_w2  = (const float*)d_in[8];
    const float* ff_b2  = (const float*)d_in[9];
    const float* ln1_g  = (const float*)d_in[10];
    const float* ln1_b  = (const float*)d_in[11];
    const float* ln2_g  = (const float*)d_in[12];
    const float* ln2_b  = (const float*)d_in[13];
    float* out = (float*)d_out;

    short* xB     = (short*)d_ws;                    // NP x 256
    short* qkvB   = xB + (size_t)NP * 256;           // NP x 768
    short* attn_o = qkvB + (size_t)NP * 768;         // NP x 256
    short* x1     = attn_o + (size_t)NP * 256;       // NP x 256
    short* hB     = x1 + (size_t)NP * 256;           // NP x 1024
    short* qkvT   = hB + (size_t)NP * 1024;          // 768 x 256
    short* outT   = qkvT + 768 * 256;                // 256 x 256
    short* ff1T   = outT + 256 * 256;                // 1024 x 256
    short* ff2T   = ff1T + 1024 * 256;               // 256 x 1024
    int* seg_s    = (int*)(ff2T + 256 * 1024);
    int* seg_e    = seg_s + NP;

    void* args[] = {
        (void*)&x, (void*)&dom, (void*)&qkv_w, (void*)&qkv_b,
        (void*)&out_w, (void*)&out_b, (void*)&ff_w1, (void*)&ff_b1,
        (void*)&ff_w2, (void*)&ff_b2, (void*)&ln1_g, (void*)&ln1_b,
        (void*)&ln2_g, (void*)&ln2_b, (void*)&out,
        (void*)&xB, (void*)&qkvB, (void*)&attn_o, (void*)&x1, (void*)&hB,
        (void*)&qkvT, (void*)&outT, (void*)&ff1T, (void*)&ff2T,
        (void*)&seg_s, (void*)&seg_e };

    hipLaunchCooperativeKernel((void*)fused_layer, dim3(256), dim3(512),
                               args, 0, stream);
}

// Round 6
// 75.737 us; speedup vs baseline: 3.9691x; 3.9691x over previous
//
#include <hip/hip_runtime.h>
#include <hip/hip_bf16.h>
#include <math.h>

constexpr int NP  = 6144;   // rows
constexpr int DM  = 256;    // d_model
constexpr int DFF = 1024;   // ff dim
constexpr float LNEPS = 1e-5f;

typedef __attribute__((ext_vector_type(8))) short short8;
typedef __attribute__((ext_vector_type(4))) short short4v;
typedef __attribute__((ext_vector_type(4))) float f32x4;

__device__ __forceinline__ short f2bf(float f) {
    unsigned u = __builtin_bit_cast(unsigned, f);
    unsigned r = u + 0x7FFFu + ((u >> 16) & 1u);   // RNE
    return (short)(r >> 16);
}
__device__ __forceinline__ float bf2f(short s) {
    unsigned u = ((unsigned)(unsigned short)s) << 16;
    return __builtin_bit_cast(float, u);
}

// global->LDS direct 16B copy. LDS dest = wave-uniform base + lane*16;
// per-lane global src carries the swizzle (guide rule #21).
#define GLOAD16(gp, lp)                                                        \
    __builtin_amdgcn_global_load_lds(                                          \
        (const __attribute__((address_space(1))) unsigned int*)(gp),           \
        (__attribute__((address_space(3))) unsigned int*)(lp), 16, 0, 0)

// LDS tile: linear [rows][64] shorts (128B row = 8 x 16B chunks); chunk c of
// row r stored at slot c ^ (r&7). Returns short index for global chunk c.
__device__ __forceinline__ int lds_idx(int row, int chunk) {
    return row * 64 + ((chunk ^ (row & 7)) * 8);
}
// Same swizzle for a [rows][256] tile (32 chunks/row; XOR touches low 3 bits).
__device__ __forceinline__ int lds_idx256(int row, int chunk) {
    return row * 256 + ((chunk ^ (row & 7)) * 8);
}

// ---------------------------------------------------------------------------
// prep: blocks 0..767 transpose+convert weights fp32[K][N] -> bf16[N][K];
// blocks 768..791 segment bounds; blocks 792..1559 convert x -> bf16.
// ---------------------------------------------------------------------------
__global__ __launch_bounds__(256) void prep_kernel(
    const float* __restrict__ qkv_w, const float* __restrict__ out_w,
    const float* __restrict__ ff_w1, const float* __restrict__ ff_w2,
    short* __restrict__ qkvT, short* __restrict__ outT,
    short* __restrict__ ff1T, short* __restrict__ ff2T,
    const int* __restrict__ dom, int* __restrict__ seg_s,
    int* __restrict__ seg_e, const float* __restrict__ x,
    short* __restrict__ xB) {
    int b = blockIdx.x;
    if (b >= 792) {   // x -> bf16
        int i = (b - 792) * 2048 + threadIdx.x * 8;
        float4 a0 = *(const float4*)&x[i];
        float4 a1 = *(const float4*)&x[i + 4];
        short8 v = { f2bf(a0.x), f2bf(a0.y), f2bf(a0.z), f2bf(a0.w),
                     f2bf(a1.x), f2bf(a1.y), f2bf(a1.z), f2bf(a1.w) };
        *(short8*)&xB[i] = v;
        return;
    }
    if (b >= 768) {   // segment bounds
        int i = (b - 768) * 256 + threadIdx.x;
        if (i >= NP) return;
        int d = dom[i];
        int s = i;
        while (s > 0 && dom[s - 1] == d) --s;
        int e = i + 1;
        while (e < NP && dom[e] == d) ++e;
        seg_s[i] = s;
        seg_e[i] = e;
        return;
    }
    const float* src;
    short* dst;
    int K, Nn;
    if (b < 192)      { src = qkv_w; dst = qkvT; K = 256;  Nn = 768; }
    else if (b < 256) { b -= 192; src = out_w; dst = outT; K = 256;  Nn = 256; }
    else if (b < 512) { b -= 256; src = ff_w1; dst = ff1T; K = 256;  Nn = 1024; }
    else              { b -= 512; src = ff_w2; dst = ff2T; K = 1024; Nn = 256; }
    int tpr = Nn / 32;
    int k0 = (b / tpr) * 32, n0 = (b % tpr) * 32;

    __shared__ float lds[32][36];
    int t = threadIdx.x;
    {
        int k = t >> 3, n = (t & 7) * 4;
        *(float4*)&lds[k][n] = *(const float4*)&src[(size_t)(k0 + k) * Nn + n0 + n];
    }
    __syncthreads();
    {
        int n = t >> 3, ks = (t & 7) * 4;
        short4v o = { f2bf(lds[ks + 0][n]), f2bf(lds[ks + 1][n]),
                      f2bf(lds[ks + 2][n]), f2bf(lds[ks + 3][n]) };
        *(short4v*)&dst[(size_t)(n0 + n) * K + k0 + ks] = o;
    }
}

// ---------------------------------------------------------------------------
// mgemm128: C_bf16[M,Nn] = A_bf16[M,K] @ Bt_bf16[Nn,K]^T + bias (opt GELU).
// Tile 128x128, BK=64, 4 waves (2x2), wave owns 64x64 = 4x4 frags.
// ---------------------------------------------------------------------------
template <bool GELU>
__global__ __launch_bounds__(256) void mgemm128(
    const short* __restrict__ A, const short* __restrict__ Bt,
    const float* __restrict__ bias, short* __restrict__ C, int Nn, int K) {
    __shared__ __align__(16) short As[128 * 64];
    __shared__ __align__(16) short Bs[128 * 64];

    const int tid = threadIdx.x, lane = tid & 63, w = tid >> 6;
    const int wm = (w >> 1) * 64, wn = (w & 1) * 64;
    const int rowBase = blockIdx.y * 128, colBase = blockIdx.x * 128;
    const int lr = lane >> 3, sc = (lane & 7) ^ lr;
    const int fr = lane & 15, g4 = lane >> 4;

    f32x4 acc[4][4];
#pragma unroll
    for (int i = 0; i < 4; ++i)
#pragma unroll
        for (int j = 0; j < 4; ++j) acc[i][j] = f32x4{0.f, 0.f, 0.f, 0.f};

    for (int k0 = 0; k0 < K; k0 += 64) {
#pragma unroll
        for (int i = 0; i < 4; ++i) {
            int g = w * 4 + i;
            int row = g * 8 + lr;
            GLOAD16(A  + (size_t)(rowBase + row) * K + k0 + sc * 8, &As[g * 512]);
            GLOAD16(Bt + (size_t)(colBase + row) * K + k0 + sc * 8, &Bs[g * 512]);
        }
        __syncthreads();

#pragma unroll
        for (int kk = 0; kk < 2; ++kk) {
            int j = kk * 4 + g4;
            short8 af[4], bfv[4];
#pragma unroll
            for (int f = 0; f < 4; ++f) {
                af[f]  = *(const short8*)&As[lds_idx(wm + f * 16 + fr, j)];
                bfv[f] = *(const short8*)&Bs[lds_idx(wn + f * 16 + fr, j)];
            }
#pragma unroll
            for (int fm = 0; fm < 4; ++fm)
#pragma unroll
                for (int fn = 0; fn < 4; ++fn)
                    acc[fm][fn] = __builtin_amdgcn_mfma_f32_16x16x32_bf16(
                        af[fm], bfv[fn], acc[fm][fn], 0, 0, 0);
        }
        __syncthreads();
    }

    const int cr = g4 * 4;
#pragma unroll
    for (int fm = 0; fm < 4; ++fm)
#pragma unroll
        for (int fn = 0; fn < 4; ++fn) {
            int c = colBase + wn + fn * 16 + fr;
            float bv = bias[c];
#pragma unroll
            for (int j = 0; j < 4; ++j) {
                int r = rowBase + wm + fm * 16 + cr + j;
                float v = acc[fm][fn][j] + bv;
                if (GELU) v = 0.5f * v * (1.0f + erff(v * 0.70710678118654752f));
                C[(size_t)r * Nn + c] = f2bf(v);
            }
        }
}

// ---------------------------------------------------------------------------
// attnln: fused {segment attention for this block's 32 rows} + {out-proj GEMM}
// + {residual + LayerNorm} -> x1 (bf16). 512 threads = 8 waves, 192 blocks.
// Attention: 8-lane groups, one (row,head) task each, 2 serial rounds; result
// stored in LDS As[32][256] (chunk-XOR swizzled), consumed as GEMM A-operand.
// ---------------------------------------------------------------------------
__global__ __launch_bounds__(512) void attnln_kernel(
    const short* __restrict__ qkvB, const int* __restrict__ seg_s,
    const int* __restrict__ seg_e, const short* __restrict__ outT,
    const float* __restrict__ out_b, const float* __restrict__ xres,
    const float* __restrict__ gw, const float* __restrict__ bw,
    short* __restrict__ x1) {
    __shared__ __align__(16) short As[32 * 256];   // attn out, swizzled
    __shared__ __align__(16) short Bs[256 * 64];
    __shared__ float r1[8][32], r2[8][32];

    const int tid = threadIdx.x, lane = tid & 63, w = tid >> 6;
    const int rowBase = blockIdx.x * 32;
    const int lr = lane >> 3, sc = (lane & 7) ^ lr;
    const int fr = lane & 15, g4 = lane >> 4;

    // ---- attention (this tile's 32 rows x 4 heads = 128 tasks) ----
    {
        const int l8 = lane & 7;
        const int G  = (w << 3) | (lane >> 3);   // 8-lane group id 0..63
#pragma unroll
        for (int s = 0; s < 2; ++s) {
            int task = G + s * 64;
            int r = task >> 2, h = task & 3;
            int row = rowBase + r;
            short8 qv = *(const short8*)&qkvB[(size_t)row * 768 + h * 64 + l8 * 8];
            float qd[8];
#pragma unroll
            for (int e = 0; e < 8; ++e) qd[e] = bf2f(qv[e]);
            int ss = seg_s[row], ee = seg_e[row];
            float m = -INFINITY, l = 0.0f;
            float acc[8] = {0.f, 0.f, 0.f, 0.f, 0.f, 0.f, 0.f, 0.f};
            for (int j = ss; j < ee; ++j) {
                short8 kv = *(const short8*)&qkvB[(size_t)j * 768 + 256 + h * 64 + l8 * 8];
                short8 vv = *(const short8*)&qkvB[(size_t)j * 768 + 512 + h * 64 + l8 * 8];
                float prod = 0.f;
#pragma unroll
                for (int e = 0; e < 8; ++e) prod += qd[e] * bf2f(kv[e]);
                prod += __shfl_xor(prod, 1);
                prod += __shfl_xor(prod, 2);
                prod += __shfl_xor(prod, 4);
                float score = prod * 0.125f;   // 1/sqrt(64)
                float mn = fmaxf(m, score);
                float scale = __expf(m - mn);
                float p = __expf(score - mn);
                l = l * scale + p;
#pragma unroll
                for (int e = 0; e < 8; ++e) acc[e] = acc[e] * scale + p * bf2f(vv[e]);
                m = mn;
            }
            float inv = 1.0f / l;
            int c = h * 8 + l8;                 // chunk 0..31
            short8 o;
#pragma unroll
            for (int e = 0; e < 8; ++e) o[e] = f2bf(acc[e] * inv);
            *(short8*)&As[r * 256 + ((c ^ (r & 7)) * 8)] = o;
        }
    }
    __syncthreads();

    // ---- GEMM (A=attn from LDS, B=outT staged) + residual + LN ----
    f32x4 acc[2][2];
#pragma unroll
    for (int i = 0; i < 2; ++i)
#pragma unroll
        for (int j = 0; j < 2; ++j) acc[i][j] = f32x4{0.f, 0.f, 0.f, 0.f};

    for (int k0 = 0; k0 < 256; k0 += 64) {
#pragma unroll
        for (int i = 0; i < 4; ++i) {            // B: 32 groups over 8 waves
            int g = w * 4 + i;
            GLOAD16(outT + (size_t)(g * 8 + lr) * 256 + k0 + sc * 8, &Bs[g * 512]);
        }
        __syncthreads();
#pragma unroll
        for (int kk = 0; kk < 2; ++kk) {
            int j = kk * 4 + g4;
            int cj = (k0 >> 3) + j;              // global chunk 0..31
            short8 af[2], bfv[2];
            af[0] = *(const short8*)&As[lds_idx256(fr, cj)];
            af[1] = *(const short8*)&As[lds_idx256(16 + fr, cj)];
#pragma unroll
            for (int fn = 0; fn < 2; ++fn)
                bfv[fn] = *(const short8*)&Bs[lds_idx(w * 32 + fn * 16 + fr, j)];
#pragma unroll
            for (int fm = 0; fm < 2; ++fm)
#pragma unroll
                for (int fn = 0; fn < 2; ++fn)
                    acc[fm][fn] = __builtin_amdgcn_mfma_f32_16x16x32_bf16(
                        af[fm], bfv[fn], acc[fm][fn], 0, 0, 0);
        }
        __syncthreads();
    }

    float v[2][2][4], p1[2][4], p2[2][4];
#pragma unroll
    for (int fm = 0; fm < 2; ++fm)
#pragma unroll
        for (int j = 0; j < 4; ++j) { p1[fm][j] = 0.f; p2[fm][j] = 0.f; }
#pragma unroll
    for (int fm = 0; fm < 2; ++fm)
#pragma unroll
        for (int fn = 0; fn < 2; ++fn) {
            int c = w * 32 + fn * 16 + fr;
            float bv = out_b[c];
#pragma unroll
            for (int j = 0; j < 4; ++j) {
                int r = rowBase + fm * 16 + g4 * 4 + j;
                float t = acc[fm][fn][j] + bv + xres[(size_t)r * 256 + c];
                v[fm][fn][j] = t;
                p1[fm][j] += t;
                p2[fm][j] += t * t;
            }
        }
#pragma unroll
    for (int m = 1; m < 16; m <<= 1)
#pragma unroll
        for (int fm = 0; fm < 2; ++fm)
#pragma unroll
            for (int j = 0; j < 4; ++j) {
                p1[fm][j] += __shfl_xor(p1[fm][j], m);
                p2[fm][j] += __shfl_xor(p2[fm][j], m);
            }
    if (fr == 0) {
#pragma unroll
        for (int fm = 0; fm < 2; ++fm)
#pragma unroll
            for (int j = 0; j < 4; ++j) {
                r1[w][fm * 16 + g4 * 4 + j] = p1[fm][j];
                r2[w][fm * 16 + g4 * 4 + j] = p2[fm][j];
            }
    }
    __syncthreads();
#pragma unroll
    for (int fm = 0; fm < 2; ++fm)
#pragma unroll
        for (int j = 0; j < 4; ++j) {
            int rl = fm * 16 + g4 * 4 + j;
            int r = rowBase + rl;
            float s1 = 0.f, s2 = 0.f;
#pragma unroll
            for (int ww = 0; ww < 8; ++ww) { s1 += r1[ww][rl]; s2 += r2[ww][rl]; }
            float mu = s1 * (1.0f / 256.0f);
            float var = s2 * (1.0f / 256.0f) - mu * mu;
            float rstd = rsqrtf(var + LNEPS);
#pragma unroll
            for (int fn = 0; fn < 2; ++fn) {
                int c = w * 32 + fn * 16 + fr;
                float o = (v[fm][fn][j] - mu) * rstd * gw[c] + bw[c];
                x1[(size_t)r * 256 + c] = f2bf(o);
            }
        }
}

// ---------------------------------------------------------------------------
// gemmln: fused C = LN( A @ Bt^T + bias + res ), Nn == 256 (full rows).
// Tile 32x256, BK=64, 4 waves; wave w owns cols [w*64, w*64+64).
// ---------------------------------------------------------------------------
template <bool RESBF, bool OUTBF>
__global__ __launch_bounds__(256) void gemmln(
    const short* __restrict__ A, const short* __restrict__ Bt,
    const float* __restrict__ bias, const void* __restrict__ resv,
    const float* __restrict__ gw, const float* __restrict__ bw,
    void* __restrict__ Cv, int K) {
    __shared__ __align__(16) short As[32 * 64];
    __shared__ __align__(16) short Bs[256 * 64];
    __shared__ float red1[4][32], red2[4][32];

    const int tid = threadIdx.x, lane = tid & 63, w = tid >> 6;
    const int rowBase = blockIdx.x * 32;
    const int lr = lane >> 3, sc = (lane & 7) ^ lr;
    const int cc = lane & 15, g4 = lane >> 4;

    f32x4 acc[2][4];
#pragma unroll
    for (int i = 0; i < 2; ++i)
#pragma unroll
        for (int j = 0; j < 4; ++j) acc[i][j] = f32x4{0.f, 0.f, 0.f, 0.f};

    for (int k0 = 0; k0 < K; k0 += 64) {
        {
            int row = w * 8 + lr;
            GLOAD16(A + (size_t)(rowBase + row) * K + k0 + sc * 8, &As[w * 512]);
        }
#pragma unroll
        for (int i = 0; i < 8; ++i) {
            int g = w * 8 + i;
            int row = g * 8 + lr;
            GLOAD16(Bt + (size_t)row * K + k0 + sc * 8, &Bs[g * 512]);
        }
        __syncthreads();

#pragma unroll
        for (int kk = 0; kk < 2; ++kk) {
            int j = kk * 4 + g4;
            short8 af[2], bfv[4];
            af[0] = *(const short8*)&As[lds_idx(cc, j)];
            af[1] = *(const short8*)&As[lds_idx(16 + cc, j)];
#pragma unroll
            for (int fn = 0; fn < 4; ++fn)
                bfv[fn] = *(const short8*)&Bs[lds_idx(w * 64 + fn * 16 + cc, j)];
#pragma unroll
            for (int fm = 0; fm < 2; ++fm)
#pragma unroll
                for (int fn = 0; fn < 4; ++fn)
                    acc[fm][fn] = __builtin_amdgcn_mfma_f32_16x16x32_bf16(
                        af[fm], bfv[fn], acc[fm][fn], 0, 0, 0);
        }
        __syncthreads();
    }

    float v[2][4][4], p1[2][4], p2[2][4];
#pragma unroll
    for (int fm = 0; fm < 2; ++fm)
#pragma unroll
        for (int j = 0; j < 4; ++j) { p1[fm][j] = 0.f; p2[fm][j] = 0.f; }

#pragma unroll
    for (int fm = 0; fm < 2; ++fm)
#pragma unroll
        for (int fn = 0; fn < 4; ++fn) {
            int c = w * 64 + fn * 16 + cc;
            float bv = bias[c];
#pragma unroll
            for (int j = 0; j < 4; ++j) {
                int r = rowBase + fm * 16 + g4 * 4 + j;
                float t = acc[fm][fn][j] + bv;
                if (RESBF) t += bf2f(((const short*)resv)[(size_t)r * 256 + c]);
                else       t += ((const float*)resv)[(size_t)r * 256 + c];
                v[fm][fn][j] = t;
                p1[fm][j] += t;
                p2[fm][j] += t * t;
            }
        }

#pragma unroll
    for (int m = 1; m < 16; m <<= 1)
#pragma unroll
        for (int fm = 0; fm < 2; ++fm)
#pragma unroll
            for (int j = 0; j < 4; ++j) {
                p1[fm][j] += __shfl_xor(p1[fm][j], m);
                p2[fm][j] += __shfl_xor(p2[fm][j], m);
            }
    if (cc == 0) {
#pragma unroll
        for (int fm = 0; fm < 2; ++fm)
#pragma unroll
            for (int j = 0; j < 4; ++j) {
                red1[w][fm * 16 + g4 * 4 + j] = p1[fm][j];
                red2[w][fm * 16 + g4 * 4 + j] = p2[fm][j];
            }
    }
    __syncthreads();

#pragma unroll
    for (int fm = 0; fm < 2; ++fm)
#pragma unroll
        for (int j = 0; j < 4; ++j) {
            int rl = fm * 16 + g4 * 4 + j;
            int r = rowBase + rl;
            float s1 = red1[0][rl] + red1[1][rl] + red1[2][rl] + red1[3][rl];
            float s2 = red2[0][rl] + red2[1][rl] + red2[2][rl] + red2[3][rl];
            float mu = s1 * (1.0f / 256.0f);
            float var = s2 * (1.0f / 256.0f) - mu * mu;
            float rstd = rsqrtf(var + LNEPS);
#pragma unroll
            for (int fn = 0; fn < 4; ++fn) {
                int c = w * 64 + fn * 16 + cc;
                float o = (v[fm][fn][j] - mu) * rstd * gw[c] + bw[c];
                if (OUTBF) ((short*)Cv)[(size_t)r * 256 + c] = f2bf(o);
                else       ((float*)Cv)[(size_t)r * 256 + c] = o;
            }
        }
}

// ---------------------------------------------------------------------------
extern "C" void kernel_launch(void* const* d_in, const int* in_sizes, int n_in,
                              void* d_out, int out_size, void* d_ws, size_t ws_size,
                              hipStream_t stream) {
    const float* x      = (const float*)d_in[0];
    const int*   dom    = (const int*)d_in[1];
    const float* qkv_w  = (const float*)d_in[2];
    const float* qkv_b  = (const float*)d_in[3];
    const float* out_w  = (const float*)d_in[4];
    const float* out_b  = (const float*)d_in[5];
    const float* ff_w1  = (const float*)d_in[6];
    const float* ff_b1  = (const float*)d_in[7];
    const float* ff_w2  = (const float*)d_in[8];
    const float* ff_b2  = (const float*)d_in[9];
    const float* ln1_g  = (const float*)d_in[10];
    const float* ln1_b  = (const float*)d_in[11];
    const float* ln2_g  = (const float*)d_in[12];
    const float* ln2_b  = (const float*)d_in[13];
    float* out = (float*)d_out;

    short* xB     = (short*)d_ws;                    // NP x 256
    short* qkvB   = xB + (size_t)NP * 256;           // NP x 768
    short* x1     = qkvB + (size_t)NP * 768;         // NP x 256
    short* hB     = x1 + (size_t)NP * 256;           // NP x 1024
    short* qkvT   = hB + (size_t)NP * 1024;          // 768 x 256
    short* outT   = qkvT + 768 * 256;                // 256 x 256
    short* ff1T   = outT + 256 * 256;                // 1024 x 256
    short* ff2T   = ff1T + 1024 * 256;               // 256 x 1024
    int* seg_s    = (int*)(ff2T + 256 * 1024);
    int* seg_e    = seg_s + NP;

    // 0) weight transpose/convert + segment bounds + x->bf16
    prep_kernel<<<1560, 256, 0, stream>>>(qkv_w, out_w, ff_w1, ff_w2,
                                          qkvT, outT, ff1T, ff2T,
                                          dom, seg_s, seg_e, x, xB);

    // 1) qkv = x @ qkv_w + qkv_b                (bf16 out)
    mgemm128<false><<<dim3(768 / 128, NP / 128), 256, 0, stream>>>(
        xB, qkvT, qkv_b, qkvB, 768, 256);

    // 2) x1 = LN1(x + attn(qkv) @ out_w + out_b)   (fused, bf16 out)
    attnln_kernel<<<NP / 32, 512, 0, stream>>>(
        qkvB, seg_s, seg_e, outT, out_b, x, ln1_g, ln1_b, x1);

    // 3) h = gelu(x1 @ ff_w1 + ff_b1)           (bf16 out)
    mgemm128<true><<<dim3(DFF / 128, NP / 128), 256, 0, stream>>>(
        x1, ff1T, ff_b1, hB, 1024, 256);

    // 4) out = LN2(x1 + h @ ff_w2 + ff_b2)      (fp32 out, bf16 residual)
    gemmln<true, false><<<NP / 32, 256, 0, stream>>>(
        hB, ff2T, ff_b2, x1, ln2_g, ln2_b, out, 1024);
}